// Round 12
// baseline (7999.995 us; speedup 1.0000x reference)
//
#include <hip/hip_runtime.h>
#include <stdint.h>

// Problem constants
#define HDIM 1024
#define NB   512
#define SEQ  128
#define VOUT 4096
#define TSTEPS 32
#define EROWS 4160   // padded E2 rows (4099 valid, rest garbage-but-deterministic)

// Output layout (float elements, concatenated in reference return order)
#define SEQ_OFF 0
#define LP_OFF  16896   // 512*33
#define ENT_OFF 33792   // 2*512*33
#define WS_OFF  50688   // 3*512*33

// ---------------------------------------------------------------- init
__global__ void init_kernel(float* __restrict__ h, int* __restrict__ tok,
                            float* __restrict__ out) {
  int idx = blockIdx.x * blockDim.x + threadIdx.x;   // 2048*256 = NB*HDIM
  h[idx] = 0.f;
  if (idx < NB) {
    tok[idx] = VOUT + 2;                             // SOS token
    out[SEQ_OFF + idx * 33 + 32] = 0.f;              // zero tail column
    out[LP_OFF  + idx * 33 + 32] = 0.f;
    out[ENT_OFF + idx * 33 + 32] = 0.f;
  }
}

// ---------------------------------------------------------------- GEMM64
// r5 proven version (rounds 7-11 verdict: 8x4 spills, dbuf trades barriers
// for occupancy -- both neutral-to-worse. This shape = 368us E2, 0 conflicts).
__global__ __launch_bounds__(256) void gemm64_kernel(
    const float* __restrict__ A, const float* __restrict__ W,
    const float* __restrict__ bias, float* __restrict__ C,
    int N, int Mlim, int KLEN, int zstride) {
  __shared__ __align__(16) float Als[32][68];
  __shared__ __align__(16) float Bls[32][68];
  const int tid = threadIdx.x;
  const int tx = tid & 15, ty = tid >> 4;
  const int m0 = blockIdx.y * 64, n0 = blockIdx.x * 64;
  const int z = blockIdx.z;
  const int kbeg = z * KLEN;
  const int sr = tid >> 3;          // 0..31
  const int scol = (tid & 7) << 2;  // 0..28

  const int ca0 = sr ^ scol;
  const int ca1 = (sr + 32) ^ scol;

  const int ra = min(m0 + sr, Mlim - 1);
  const int rb = min(m0 + sr + 32, Mlim - 1);
  const float* a0 = A + (size_t)ra * HDIM + kbeg + scol;
  const float* a1 = A + (size_t)rb * HDIM + kbeg + scol;
  const float* w0 = W + (size_t)(n0 + sr) * HDIM + kbeg + scol;
  const float* w1 = W + (size_t)(n0 + sr + 32) * HDIM + kbeg + scol;

  float accT[4][4];
#pragma unroll
  for (int i = 0; i < 4; ++i)
#pragma unroll
    for (int j = 0; j < 4; ++j) accT[i][j] = 0.f;

  float4 av0 = *(const float4*)(a0);
  float4 av1 = *(const float4*)(a1);
  float4 wv0 = *(const float4*)(w0);
  float4 wv1 = *(const float4*)(w1);

  for (int k0 = 0; k0 < KLEN; k0 += 32) {
    __syncthreads();
    Als[scol + 0][ca0] = av0.x; Als[scol + 1][ca0] = av0.y;
    Als[scol + 2][ca0] = av0.z; Als[scol + 3][ca0] = av0.w;
    Als[scol + 0][ca1] = av1.x; Als[scol + 1][ca1] = av1.y;
    Als[scol + 2][ca1] = av1.z; Als[scol + 3][ca1] = av1.w;
    Bls[scol + 0][ca0] = wv0.x; Bls[scol + 1][ca0] = wv0.y;
    Bls[scol + 2][ca0] = wv0.z; Bls[scol + 3][ca0] = wv0.w;
    Bls[scol + 0][ca1] = wv1.x; Bls[scol + 1][ca1] = wv1.y;
    Bls[scol + 2][ca1] = wv1.z; Bls[scol + 3][ca1] = wv1.w;
    __syncthreads();

    {
      const int kn = min(k0 + 32, KLEN - 32);
      av0 = *(const float4*)(a0 + kn);
      av1 = *(const float4*)(a1 + kn);
      wv0 = *(const float4*)(w0 + kn);
      wv1 = *(const float4*)(w1 + kn);
    }

    // chunk accumulator (flushed per BK) keeps error ~5 eps
    float ac[4][4];
#pragma unroll
    for (int i = 0; i < 4; ++i)
#pragma unroll
      for (int j = 0; j < 4; ++j) ac[i][j] = 0.f;

#pragma unroll
    for (int kk = 0; kk < 32; ++kk) {
      const int sz = kk & 28;  // read swizzle (wave-uniform, bits 2-4)
      float4 a4 = *(const float4*)&Als[kk][(ty * 4) ^ sz];
      float4 b4 = *(const float4*)&Bls[kk][(tx * 4) ^ sz];
      float a_[4] = {a4.x, a4.y, a4.z, a4.w};
      float b_[4] = {b4.x, b4.y, b4.z, b4.w};
#pragma unroll
      for (int i = 0; i < 4; ++i)
#pragma unroll
        for (int j = 0; j < 4; ++j) ac[i][j] = fmaf(a_[i], b_[j], ac[i][j]);
    }
#pragma unroll
    for (int i = 0; i < 4; ++i)
#pragma unroll
      for (int j = 0; j < 4; ++j) accT[i][j] += ac[i][j];
  }

  float* Cz = C + (size_t)z * zstride;
  float b0 = 0.f, b1 = 0.f, b2 = 0.f, b3 = 0.f;
  if (z == 0) {
    b0 = bias[n0 + tx * 4 + 0];
    b1 = bias[n0 + tx * 4 + 1];
    b2 = bias[n0 + tx * 4 + 2];
    b3 = bias[n0 + tx * 4 + 3];
  }
#pragma unroll
  for (int i = 0; i < 4; ++i) {
    int m = m0 + ty * 4 + i;
    float4 o;
    o.x = accT[i][0] + b0;
    o.y = accT[i][1] + b1;
    o.z = accT[i][2] + b2;
    o.w = accT[i][3] + b3;
    *(float4*)&Cz[(size_t)m * N + n0 + tx * 4] = o;
  }
}

// ---------------------------------------------------------------- gate (pre-loop only)
__global__ __launch_bounds__(256) void gate_kernel(
    const float* __restrict__ E2, const float* __restrict__ gh,
    const int* __restrict__ tok, float* __restrict__ h) {
  int idx = blockIdx.x * blockDim.x + threadIdx.x;
  int b = idx >> 8;
  int c = (idx & 255) << 2;
  const float* e = E2 + (size_t)tok[b] * (3 * HDIM) + c;
  const float* g0 = gh + (size_t)b * (3 * HDIM) + c;
  const float* g1 = g0 + (size_t)NB * 3 * HDIM;
  float4 ir = *(const float4*)(e);
  float4 iz = *(const float4*)(e + HDIM);
  float4 in_ = *(const float4*)(e + 2 * HDIM);
  float4 hra = *(const float4*)(g0);
  float4 hza = *(const float4*)(g0 + HDIM);
  float4 hna = *(const float4*)(g0 + 2 * HDIM);
  float4 hrb = *(const float4*)(g1);
  float4 hzb = *(const float4*)(g1 + HDIM);
  float4 hnb = *(const float4*)(g1 + 2 * HDIM);
  float4 hv = *(const float4*)&h[(size_t)b * HDIM + c];
  float4 o;
  {
    float r = 1.f / (1.f + expf(-(ir.x + hra.x + hrb.x)));
    float z = 1.f / (1.f + expf(-(iz.x + hza.x + hzb.x)));
    float n = tanhf(in_.x + r * (hna.x + hnb.x));
    o.x = (1.f - z) * n + z * hv.x;
  }
  {
    float r = 1.f / (1.f + expf(-(ir.y + hra.y + hrb.y)));
    float z = 1.f / (1.f + expf(-(iz.y + hza.y + hzb.y)));
    float n = tanhf(in_.y + r * (hna.y + hnb.y));
    o.y = (1.f - z) * n + z * hv.y;
  }
  {
    float r = 1.f / (1.f + expf(-(ir.z + hra.z + hrb.z)));
    float z = 1.f / (1.f + expf(-(iz.z + hza.z + hzb.z)));
    float n = tanhf(in_.z + r * (hna.z + hnb.z));
    o.z = (1.f - z) * n + z * hv.z;
  }
  {
    float r = 1.f / (1.f + expf(-(ir.w + hra.w + hrb.w)));
    float z = 1.f / (1.f + expf(-(iz.w + hza.w + hzb.w)));
    float n = tanhf(in_.w + r * (hna.w + hnb.w));
    o.w = (1.f - z) * n + z * hv.w;
  }
  *(float4*)&h[(size_t)b * HDIM + c] = o;
}

// ---------------------------------------------------------------- attn + gh (merged)
// Blocks [0, nattn): fused one-pass attention on h_t (latency-bound fix:
// contiguous 16-key chunk per wave + distance-1 register prefetch).
// Blocks [nattn, nattn+384): gh_{t+1} partials = h_t @ W_hh^T (VALU-bound).
#define SMEM_BYTES 37440
__global__ __launch_bounds__(512) void attn_gh_kernel(
    const float* __restrict__ h, const float* __restrict__ enc,
    const float* __restrict__ sem, const float* __restrict__ emb,
    float* __restrict__ x, float* __restrict__ out, int t,
    const float* __restrict__ W_hh, const float* __restrict__ b_hh,
    float* __restrict__ gh, int nattn) {
  __shared__ __align__(16) char smem[SMEM_BYTES];
  const int tid = threadIdx.x;
  if ((int)blockIdx.x < nattn) {
    // ------------- attention branch (8 waves, 16 contiguous keys each)
    float* hs = reinterpret_cast<float*>(smem);                         // [1024]
    float (*accb)[HDIM] = reinterpret_cast<float (*)[HDIM]>(smem + 4096); // [8][1024]
    float* uls = reinterpret_cast<float*>(smem + 36864);                // [129]
    float* usums = reinterpret_cast<float*>(smem + 37392);              // [8]
    const int b = blockIdx.x;
    const int lane = tid & 63, wv = tid >> 6;

    *(float2*)&hs[tid * 2] = *(const float2*)&h[(size_t)b * HDIM + tid * 2];
    __syncthreads();

    const int l4 = lane * 4;
    float4 hv0 = *(const float4*)&hs[l4];
    float4 hv1 = *(const float4*)&hs[l4 + 256];
    float4 hv2 = *(const float4*)&hs[l4 + 512];
    float4 hv3 = *(const float4*)&hs[l4 + 768];

    float4 acc0 = {0, 0, 0, 0}, acc1 = {0, 0, 0, 0};
    float4 acc2 = {0, 0, 0, 0}, acc3 = {0, 0, 0, 0};
    float usum = 0.f;

    // wave wv streams keys [wv*16, wv*16+16): contiguous 64KB enc + 64KB sem
    const float* erow = enc + ((size_t)b * SEQ + wv * 16) * HDIM + l4;
    const float* vrow = sem + ((size_t)b * SEQ + wv * 16) * HDIM + l4;

    // preload row 0 of this wave's chunk
    float4 e0 = *(const float4*)(erow);
    float4 e1 = *(const float4*)(erow + 256);
    float4 e2 = *(const float4*)(erow + 512);
    float4 e3 = *(const float4*)(erow + 768);
    float4 v0 = *(const float4*)(vrow);
    float4 v1 = *(const float4*)(vrow + 256);
    float4 v2 = *(const float4*)(vrow + 512);
    float4 v3 = *(const float4*)(vrow + 768);

#pragma unroll 2
    for (int j = 0; j < 16; ++j) {
      // distance-1 prefetch: issue row j+1's loads BEFORE computing row j
      // (j=15 harmlessly reloads row 15; copies below are then dead)
      const size_t noff = (size_t)(j < 15 ? j + 1 : 15) * HDIM;
      float4 f0 = *(const float4*)(erow + noff);
      float4 f1 = *(const float4*)(erow + noff + 256);
      float4 f2 = *(const float4*)(erow + noff + 512);
      float4 f3 = *(const float4*)(erow + noff + 768);
      float4 g0 = *(const float4*)(vrow + noff);
      float4 g1 = *(const float4*)(vrow + noff + 256);
      float4 g2 = *(const float4*)(vrow + noff + 512);
      float4 g3 = *(const float4*)(vrow + noff + 768);

      float p = 0.f;
      p = fmaf(e0.x, hv0.x, p); p = fmaf(e0.y, hv0.y, p);
      p = fmaf(e0.z, hv0.z, p); p = fmaf(e0.w, hv0.w, p);
      p = fmaf(e1.x, hv1.x, p); p = fmaf(e1.y, hv1.y, p);
      p = fmaf(e1.z, hv1.z, p); p = fmaf(e1.w, hv1.w, p);
      p = fmaf(e2.x, hv2.x, p); p = fmaf(e2.y, hv2.y, p);
      p = fmaf(e2.z, hv2.z, p); p = fmaf(e2.w, hv2.w, p);
      p = fmaf(e3.x, hv3.x, p); p = fmaf(e3.y, hv3.y, p);
      p = fmaf(e3.z, hv3.z, p); p = fmaf(e3.w, hv3.w, p);
#pragma unroll
      for (int off = 32; off; off >>= 1) p += __shfl_xor(p, off);

      float u = expf(p * 0.03125f);  // * 1/sqrt(1024)
      usum += u;
      if (lane == 0) uls[wv * 16 + j] = u;

      acc0.x = fmaf(u, v0.x, acc0.x); acc0.y = fmaf(u, v0.y, acc0.y);
      acc0.z = fmaf(u, v0.z, acc0.z); acc0.w = fmaf(u, v0.w, acc0.w);
      acc1.x = fmaf(u, v1.x, acc1.x); acc1.y = fmaf(u, v1.y, acc1.y);
      acc1.z = fmaf(u, v1.z, acc1.z); acc1.w = fmaf(u, v1.w, acc1.w);
      acc2.x = fmaf(u, v2.x, acc2.x); acc2.y = fmaf(u, v2.y, acc2.y);
      acc2.z = fmaf(u, v2.z, acc2.z); acc2.w = fmaf(u, v2.w, acc2.w);
      acc3.x = fmaf(u, v3.x, acc3.x); acc3.y = fmaf(u, v3.y, acc3.y);
      acc3.z = fmaf(u, v3.z, acc3.z); acc3.w = fmaf(u, v3.w, acc3.w);

      e0 = f0; e1 = f1; e2 = f2; e3 = f3;
      v0 = g0; v1 = g1; v2 = g2; v3 = g3;
    }

    // EOS key (k = 128): handled once by wave 0 (wave-uniform branch)
    if (wv == 0) {
      const float* kr = emb + (size_t)VOUT * HDIM + l4;
      const float* vr = emb + (size_t)(VOUT + 1) * HDIM + l4;
      float4 q0 = *(const float4*)(kr);
      float4 q1 = *(const float4*)(kr + 256);
      float4 q2 = *(const float4*)(kr + 512);
      float4 q3 = *(const float4*)(kr + 768);
      float4 w0_ = *(const float4*)(vr);
      float4 w1_ = *(const float4*)(vr + 256);
      float4 w2_ = *(const float4*)(vr + 512);
      float4 w3_ = *(const float4*)(vr + 768);
      float p = 0.f;
      p = fmaf(q0.x, hv0.x, p); p = fmaf(q0.y, hv0.y, p);
      p = fmaf(q0.z, hv0.z, p); p = fmaf(q0.w, hv0.w, p);
      p = fmaf(q1.x, hv1.x, p); p = fmaf(q1.y, hv1.y, p);
      p = fmaf(q1.z, hv1.z, p); p = fmaf(q1.w, hv1.w, p);
      p = fmaf(q2.x, hv2.x, p); p = fmaf(q2.y, hv2.y, p);
      p = fmaf(q2.z, hv2.z, p); p = fmaf(q2.w, hv2.w, p);
      p = fmaf(q3.x, hv3.x, p); p = fmaf(q3.y, hv3.y, p);
      p = fmaf(q3.z, hv3.z, p); p = fmaf(q3.w, hv3.w, p);
#pragma unroll
      for (int off = 32; off; off >>= 1) p += __shfl_xor(p, off);
      float u = expf(p * 0.03125f);
      usum += u;
      if (lane == 0) uls[SEQ] = u;
      acc0.x = fmaf(u, w0_.x, acc0.x); acc0.y = fmaf(u, w0_.y, acc0.y);
      acc0.z = fmaf(u, w0_.z, acc0.z); acc0.w = fmaf(u, w0_.w, acc0.w);
      acc1.x = fmaf(u, w1_.x, acc1.x); acc1.y = fmaf(u, w1_.y, acc1.y);
      acc1.z = fmaf(u, w1_.z, acc1.z); acc1.w = fmaf(u, w1_.w, acc1.w);
      acc2.x = fmaf(u, w2_.x, acc2.x); acc2.y = fmaf(u, w2_.y, acc2.y);
      acc2.z = fmaf(u, w2_.z, acc2.z); acc2.w = fmaf(u, w2_.w, acc2.w);
      acc3.x = fmaf(u, w3_.x, acc3.x); acc3.y = fmaf(u, w3_.y, acc3.y);
      acc3.z = fmaf(u, w3_.z, acc3.z); acc3.w = fmaf(u, w3_.w, acc3.w);
    }

    if (lane == 0) usums[wv] = usum;
    *(float4*)&accb[wv][l4] = acc0;
    *(float4*)&accb[wv][l4 + 256] = acc1;
    *(float4*)&accb[wv][l4 + 512] = acc2;
    *(float4*)&accb[wv][l4 + 768] = acc3;
    __syncthreads();

    float U = 0.f;
#pragma unroll
    for (int w = 0; w < 8; ++w) U += usums[w];
    float rinv = 1.f / U;

#pragma unroll
    for (int dd = 0; dd < 2; ++dd) {
      int d = tid + dd * 512;
      float sum = 0.f;
#pragma unroll
      for (int w = 0; w < 8; ++w) sum += accb[w][d];
      x[(size_t)b * HDIM + d] = sum * rinv + hs[d];
    }

    if (tid < SEQ + 1)
      out[WS_OFF + ((size_t)b * TSTEPS + t) * (SEQ + 1) + tid] = uls[tid] * rinv;
  } else {
    // ------------- gh GEMM branch: BM=128, BN=64, BK=32, K-split 2
    float (*Als)[132] = reinterpret_cast<float (*)[132]>(smem);          // 16896 B
    float (*Bls)[68] = reinterpret_cast<float (*)[68]>(smem + 16896);    // 8704 B
    int gb = blockIdx.x - nattn;
    const int z = gb / 192; gb -= z * 192;
    const int by = gb / 48, bx = gb - by * 48;
    const int m0 = by * 128, n0 = bx * 64;
    const int kbeg = z * 512;
    const int tx = tid & 15, ty = tid >> 4;   // ty 0..31 (A rows), tx 0..15 (B cols)
    const int sr = tid >> 3;                  // 0..63
    const int scol = (tid & 7) << 2;          // 0..28
    const int ca = sr ^ scol;

    const float* a0 = h + (size_t)(m0 + sr) * HDIM + kbeg + scol;
    const float* a1 = h + (size_t)(m0 + sr + 64) * HDIM + kbeg + scol;
    const float* w0 = W_hh + (size_t)(n0 + sr) * HDIM + kbeg + scol;

    float accT[4][4];
#pragma unroll
    for (int i = 0; i < 4; ++i)
#pragma unroll
      for (int j = 0; j < 4; ++j) accT[i][j] = 0.f;

    float4 av0 = *(const float4*)(a0);
    float4 av1 = *(const float4*)(a1);
    float4 wv0 = *(const float4*)(w0);

    for (int k0 = 0; k0 < 512; k0 += 32) {
      __syncthreads();
      Als[scol + 0][ca] = av0.x; Als[scol + 1][ca] = av0.y;
      Als[scol + 2][ca] = av0.z; Als[scol + 3][ca] = av0.w;
      Als[scol + 0][ca + 64] = av1.x; Als[scol + 1][ca + 64] = av1.y;
      Als[scol + 2][ca + 64] = av1.z; Als[scol + 3][ca + 64] = av1.w;
      Bls[scol + 0][ca] = wv0.x; Bls[scol + 1][ca] = wv0.y;
      Bls[scol + 2][ca] = wv0.z; Bls[scol + 3][ca] = wv0.w;
      __syncthreads();

      {
        const int kn = min(k0 + 32, 512 - 32);
        av0 = *(const float4*)(a0 + kn);
        av1 = *(const float4*)(a1 + kn);
        wv0 = *(const float4*)(w0 + kn);
      }

      float ac[4][4];
#pragma unroll
      for (int i = 0; i < 4; ++i)
#pragma unroll
        for (int j = 0; j < 4; ++j) ac[i][j] = 0.f;

#pragma unroll
      for (int kk = 0; kk < 32; ++kk) {
        const int sz = kk & 28;
        float4 a4 = *(const float4*)&Als[kk][(ty * 4) ^ sz];
        float4 b4 = *(const float4*)&Bls[kk][(tx * 4) ^ sz];
        float a_[4] = {a4.x, a4.y, a4.z, a4.w};
        float b_[4] = {b4.x, b4.y, b4.z, b4.w};
#pragma unroll
        for (int i = 0; i < 4; ++i)
#pragma unroll
          for (int j = 0; j < 4; ++j) ac[i][j] = fmaf(a_[i], b_[j], ac[i][j]);
      }
#pragma unroll
      for (int i = 0; i < 4; ++i)
#pragma unroll
        for (int j = 0; j < 4; ++j) accT[i][j] += ac[i][j];
    }

    float* Cz = gh + (size_t)z * (NB * 3 * HDIM);
    float b0 = 0.f, b1 = 0.f, b2 = 0.f, b3 = 0.f;
    if (z == 0) {
      b0 = b_hh[n0 + tx * 4 + 0];
      b1 = b_hh[n0 + tx * 4 + 1];
      b2 = b_hh[n0 + tx * 4 + 2];
      b3 = b_hh[n0 + tx * 4 + 3];
    }
#pragma unroll
    for (int i = 0; i < 4; ++i) {
      int m = m0 + ty * 4 + i;
      float4 o;
      o.x = accT[i][0] + b0;
      o.y = accT[i][1] + b1;
      o.z = accT[i][2] + b2;
      o.w = accT[i][3] + b3;
      *(float4*)&Cz[(size_t)m * (3 * HDIM) + n0 + tx * 4] = o;
    }
  }
}

// ---------------------------------------------------------------- finalize + gate
// logits = z0 + z1 (K-split planes). Single pass: argmax/lse/entropy, then
// apply next step's GRU gate for row b -> h_{t+1}.
__global__ __launch_bounds__(256) void finalgate_kernel(
    const float* __restrict__ logits, float* __restrict__ out, int t,
    const float* __restrict__ E2, const float* __restrict__ gh,
    float* __restrict__ h) {
  const int b = blockIdx.x, tid = threadIdx.x;
  const int lane = tid & 63, wv = tid >> 6;
  const float* lrow0 = logits + (size_t)b * VOUT;
  const float* lrow1 = lrow0 + (size_t)NB * VOUT;
  float m = -3.4e38f; int mi = 0;
  float s = 0.f, ts = 0.f;
#pragma unroll
  for (int it = 0; it < 4; ++it) {
    int j = (tid << 2) + (it << 10);
    float4 va = *(const float4*)&lrow0[j];
    float4 vb = *(const float4*)&lrow1[j];
    float4 v;
    v.x = va.x + vb.x; v.y = va.y + vb.y; v.z = va.z + vb.z; v.w = va.w + vb.w;
    float e;
    e = expf(v.x); s += e; ts = fmaf(e, v.x, ts); if (v.x > m) { m = v.x; mi = j; }
    e = expf(v.y); s += e; ts = fmaf(e, v.y, ts); if (v.y > m) { m = v.y; mi = j + 1; }
    e = expf(v.z); s += e; ts = fmaf(e, v.z, ts); if (v.z > m) { m = v.z; mi = j + 2; }
    e = expf(v.w); s += e; ts = fmaf(e, v.w, ts); if (v.w > m) { m = v.w; mi = j + 3; }
  }
#pragma unroll
  for (int off = 32; off; off >>= 1) {
    float om = __shfl_xor(m, off);
    int oi = __shfl_xor(mi, off);
    s += __shfl_xor(s, off);
    ts += __shfl_xor(ts, off);
    if (om > m || (om == m && oi < mi)) { m = om; mi = oi; }
  }
  __shared__ float smx[4], ssm[4], sts[4];
  __shared__ int smi[4];
  __shared__ int mib;
  if (lane == 0) { smx[wv] = m; smi[wv] = mi; ssm[wv] = s; sts[wv] = ts; }
  __syncthreads();
  if (tid == 0) {
#pragma unroll
    for (int w = 1; w < 4; ++w) {
      s += ssm[w]; ts += sts[w];
      if (smx[w] > m || (smx[w] == m && smi[w] < mi)) { m = smx[w]; mi = smi[w]; }
    }
    float lse = logf(s);
    float lp = m - lse;
    float ent = lse - ts / s;
    out[SEQ_OFF + (size_t)b * 33 + t] = (float)mi;
    out[LP_OFF  + (size_t)b * 33 + t] = lp;
    out[ENT_OFF + (size_t)b * 33 + t] = ent;
    mib = mi;
  }
  __syncthreads();

  // ---- gate for next step: h[b] = GRU(E2[mib], gh[b], h[b])
  const int c = tid << 2;
  const float* e = E2 + (size_t)mib * (3 * HDIM) + c;
  const float* g0 = gh + (size_t)b * (3 * HDIM) + c;
  const float* g1 = g0 + (size_t)NB * 3 * HDIM;
  float4 ir = *(const float4*)(e);
  float4 iz = *(const float4*)(e + HDIM);
  float4 in_ = *(const float4*)(e + 2 * HDIM);
  float4 hra = *(const float4*)(g0);
  float4 hza = *(const float4*)(g0 + HDIM);
  float4 hna = *(const float4*)(g0 + 2 * HDIM);
  float4 hrb = *(const float4*)(g1);
  float4 hzb = *(const float4*)(g1 + HDIM);
  float4 hnb = *(const float4*)(g1 + 2 * HDIM);
  float4 hv = *(const float4*)&h[(size_t)b * HDIM + c];
  float4 o;
  {
    float r = 1.f / (1.f + expf(-(ir.x + hra.x + hrb.x)));
    float z = 1.f / (1.f + expf(-(iz.x + hza.x + hzb.x)));
    float n = tanhf(in_.x + r * (hna.x + hnb.x));
    o.x = (1.f - z) * n + z * hv.x;
  }
  {
    float r = 1.f / (1.f + expf(-(ir.y + hra.y + hrb.y)));
    float z = 1.f / (1.f + expf(-(iz.y + hza.y + hzb.y)));
    float n = tanhf(in_.y + r * (hna.y + hnb.y));
    o.y = (1.f - z) * n + z * hv.y;
  }
  {
    float r = 1.f / (1.f + expf(-(ir.z + hra.z + hrb.z)));
    float z = 1.f / (1.f + expf(-(iz.z + hza.z + hzb.z)));
    float n = tanhf(in_.z + r * (hna.z + hnb.z));
    o.z = (1.f - z) * n + z * hv.z;
  }
  {
    float r = 1.f / (1.f + expf(-(ir.w + hra.w + hrb.w)));
    float z = 1.f / (1.f + expf(-(iz.w + hza.w + hzb.w)));
    float n = tanhf(in_.w + r * (hna.w + hnb.w));
    o.w = (1.f - z) * n + z * hv.w;
  }
  *(float4*)&h[(size_t)b * HDIM + c] = o;
}

// ---------------------------------------------------------------- launch
extern "C" void kernel_launch(void* const* d_in, const int* in_sizes, int n_in,
                              void* d_out, int out_size, void* d_ws, size_t ws_size,
                              hipStream_t stream) {
  const float* enc   = (const float*)d_in[0];
  const float* sem   = (const float*)d_in[1];
  const float* emb   = (const float*)d_in[2];
  const float* W_ih  = (const float*)d_in[3];
  const float* W_hh  = (const float*)d_in[4];
  const float* b_ih  = (const float*)d_in[5];
  const float* b_hh  = (const float*)d_in[6];
  const float* W_out = (const float*)d_in[7];
  const float* b_out = (const float*)d_in[8];
  float* out = (float*)d_out;

  float* h      = (float*)d_ws;                        // 512*1024
  float* x      = h + (size_t)NB * HDIM;               // 512*1024
  float* gh     = x + (size_t)NB * HDIM;               // 2 * 512*3072 (K-split)
  float* logits = gh + (size_t)2 * NB * 3 * HDIM;      // 2 * 512*4096 (K-split)
  float* E2     = logits + (size_t)2 * NB * VOUT;      // 4160*3072
  int*   tok    = (int*)(E2 + (size_t)EROWS * 3 * HDIM);

  init_kernel<<<2048, 256, 0, stream>>>(h, tok, out);
  // E2 = embedding @ W_ih^T + b_ih  (once per launch; rows clamped at 4099)
  gemm64_kernel<<<dim3(48, 65, 1), 256, 0, stream>>>(emb, W_ih, b_ih, E2,
                                                     3 * HDIM, VOUT + 3, HDIM, 0);
  // gh_0 partials from h=0 (gemm branch only), then gate_0 with SOS tokens
  attn_gh_kernel<<<384, 512, 0, stream>>>(h, enc, sem, emb, x, out, 0,
                                          W_hh, b_hh, gh, 0);
  gate_kernel<<<512, 256, 0, stream>>>(E2, gh, tok, h);

  for (int t = 0; t < TSTEPS; ++t) {
    // attn_t (512 blocks) || gh_{t+1} partials (384 blocks)
    attn_gh_kernel<<<896, 512, 0, stream>>>(h, enc, sem, emb, x, out, t,
                                            W_hh, b_hh, gh, 512);
    // logits partials: K-split=2 -> 1024 blocks (4/CU)
    gemm64_kernel<<<dim3(64, 8, 2), 256, 0, stream>>>(x, W_out, b_out, logits,
                                                      VOUT, NB, HDIM / 2,
                                                      NB * VOUT);
    finalgate_kernel<<<512, 256, 0, stream>>>(logits, out, t, E2, gh, h);
  }
}

// Round 13
// 7514.603 us; speedup vs baseline: 1.0646x; 1.0646x over previous
//
#include <hip/hip_runtime.h>
#include <stdint.h>

// Problem constants
#define HDIM 1024
#define NB   512
#define SEQ  128
#define VOUT 4096
#define TSTEPS 32
#define EROWS 4160   // padded E2 rows (4099 valid, rest garbage-but-deterministic)

// Output layout (float elements, concatenated in reference return order)
#define SEQ_OFF 0
#define LP_OFF  16896   // 512*33
#define ENT_OFF 33792   // 2*512*33
#define WS_OFF  50688   // 3*512*33

// ---------------------------------------------------------------- init
__global__ void init_kernel(float* __restrict__ h, int* __restrict__ tok,
                            float* __restrict__ out) {
  int idx = blockIdx.x * blockDim.x + threadIdx.x;   // 2048*256 = NB*HDIM
  h[idx] = 0.f;
  if (idx < NB) {
    tok[idx] = VOUT + 2;                             // SOS token
    out[SEQ_OFF + idx * 33 + 32] = 0.f;              // zero tail column
    out[LP_OFF  + idx * 33 + 32] = 0.f;
    out[ENT_OFF + idx * 33 + 32] = 0.f;
  }
}

// ---------------------------------------------------------------- GEMM64
// r5 proven version (rounds 7-11 verdict: 8x4 spills, dbuf trades barriers
// for occupancy -- both neutral-to-worse. This shape = 368us E2, 0 conflicts).
__global__ __launch_bounds__(256) void gemm64_kernel(
    const float* __restrict__ A, const float* __restrict__ W,
    const float* __restrict__ bias, float* __restrict__ C,
    int N, int Mlim, int KLEN, int zstride) {
  __shared__ __align__(16) float Als[32][68];
  __shared__ __align__(16) float Bls[32][68];
  const int tid = threadIdx.x;
  const int tx = tid & 15, ty = tid >> 4;
  const int m0 = blockIdx.y * 64, n0 = blockIdx.x * 64;
  const int z = blockIdx.z;
  const int kbeg = z * KLEN;
  const int sr = tid >> 3;          // 0..31
  const int scol = (tid & 7) << 2;  // 0..28

  const int ca0 = sr ^ scol;
  const int ca1 = (sr + 32) ^ scol;

  const int ra = min(m0 + sr, Mlim - 1);
  const int rb = min(m0 + sr + 32, Mlim - 1);
  const float* a0 = A + (size_t)ra * HDIM + kbeg + scol;
  const float* a1 = A + (size_t)rb * HDIM + kbeg + scol;
  const float* w0 = W + (size_t)(n0 + sr) * HDIM + kbeg + scol;
  const float* w1 = W + (size_t)(n0 + sr + 32) * HDIM + kbeg + scol;

  float accT[4][4];
#pragma unroll
  for (int i = 0; i < 4; ++i)
#pragma unroll
    for (int j = 0; j < 4; ++j) accT[i][j] = 0.f;

  float4 av0 = *(const float4*)(a0);
  float4 av1 = *(const float4*)(a1);
  float4 wv0 = *(const float4*)(w0);
  float4 wv1 = *(const float4*)(w1);

  for (int k0 = 0; k0 < KLEN; k0 += 32) {
    __syncthreads();
    Als[scol + 0][ca0] = av0.x; Als[scol + 1][ca0] = av0.y;
    Als[scol + 2][ca0] = av0.z; Als[scol + 3][ca0] = av0.w;
    Als[scol + 0][ca1] = av1.x; Als[scol + 1][ca1] = av1.y;
    Als[scol + 2][ca1] = av1.z; Als[scol + 3][ca1] = av1.w;
    Bls[scol + 0][ca0] = wv0.x; Bls[scol + 1][ca0] = wv0.y;
    Bls[scol + 2][ca0] = wv0.z; Bls[scol + 3][ca0] = wv0.w;
    Bls[scol + 0][ca1] = wv1.x; Bls[scol + 1][ca1] = wv1.y;
    Bls[scol + 2][ca1] = wv1.z; Bls[scol + 3][ca1] = wv1.w;
    __syncthreads();

    {
      const int kn = min(k0 + 32, KLEN - 32);
      av0 = *(const float4*)(a0 + kn);
      av1 = *(const float4*)(a1 + kn);
      wv0 = *(const float4*)(w0 + kn);
      wv1 = *(const float4*)(w1 + kn);
    }

    // chunk accumulator (flushed per BK) keeps error ~5 eps
    float ac[4][4];
#pragma unroll
    for (int i = 0; i < 4; ++i)
#pragma unroll
      for (int j = 0; j < 4; ++j) ac[i][j] = 0.f;

#pragma unroll
    for (int kk = 0; kk < 32; ++kk) {
      const int sz = kk & 28;  // read swizzle (wave-uniform, bits 2-4)
      float4 a4 = *(const float4*)&Als[kk][(ty * 4) ^ sz];
      float4 b4 = *(const float4*)&Bls[kk][(tx * 4) ^ sz];
      float a_[4] = {a4.x, a4.y, a4.z, a4.w};
      float b_[4] = {b4.x, b4.y, b4.z, b4.w};
#pragma unroll
      for (int i = 0; i < 4; ++i)
#pragma unroll
        for (int j = 0; j < 4; ++j) ac[i][j] = fmaf(a_[i], b_[j], ac[i][j]);
    }
#pragma unroll
    for (int i = 0; i < 4; ++i)
#pragma unroll
      for (int j = 0; j < 4; ++j) accT[i][j] += ac[i][j];
  }

  float* Cz = C + (size_t)z * zstride;
  float b0 = 0.f, b1 = 0.f, b2 = 0.f, b3 = 0.f;
  if (z == 0) {
    b0 = bias[n0 + tx * 4 + 0];
    b1 = bias[n0 + tx * 4 + 1];
    b2 = bias[n0 + tx * 4 + 2];
    b3 = bias[n0 + tx * 4 + 3];
  }
#pragma unroll
  for (int i = 0; i < 4; ++i) {
    int m = m0 + ty * 4 + i;
    float4 o;
    o.x = accT[i][0] + b0;
    o.y = accT[i][1] + b1;
    o.z = accT[i][2] + b2;
    o.w = accT[i][3] + b3;
    *(float4*)&Cz[(size_t)m * N + n0 + tx * 4] = o;
  }
}

// ---------------------------------------------------------------- gate (pre-loop only)
__global__ __launch_bounds__(256) void gate_kernel(
    const float* __restrict__ E2, const float* __restrict__ gh,
    const int* __restrict__ tok, float* __restrict__ h) {
  int idx = blockIdx.x * blockDim.x + threadIdx.x;
  int b = idx >> 8;
  int c = (idx & 255) << 2;
  const float* e = E2 + (size_t)tok[b] * (3 * HDIM) + c;
  const float* g0 = gh + (size_t)b * (3 * HDIM) + c;
  const float* g1 = g0 + (size_t)NB * 3 * HDIM;
  float4 ir = *(const float4*)(e);
  float4 iz = *(const float4*)(e + HDIM);
  float4 in_ = *(const float4*)(e + 2 * HDIM);
  float4 hra = *(const float4*)(g0);
  float4 hza = *(const float4*)(g0 + HDIM);
  float4 hna = *(const float4*)(g0 + 2 * HDIM);
  float4 hrb = *(const float4*)(g1);
  float4 hzb = *(const float4*)(g1 + HDIM);
  float4 hnb = *(const float4*)(g1 + 2 * HDIM);
  float4 hv = *(const float4*)&h[(size_t)b * HDIM + c];
  float4 o;
  {
    float r = 1.f / (1.f + expf(-(ir.x + hra.x + hrb.x)));
    float z = 1.f / (1.f + expf(-(iz.x + hza.x + hzb.x)));
    float n = tanhf(in_.x + r * (hna.x + hnb.x));
    o.x = (1.f - z) * n + z * hv.x;
  }
  {
    float r = 1.f / (1.f + expf(-(ir.y + hra.y + hrb.y)));
    float z = 1.f / (1.f + expf(-(iz.y + hza.y + hzb.y)));
    float n = tanhf(in_.y + r * (hna.y + hnb.y));
    o.y = (1.f - z) * n + z * hv.y;
  }
  {
    float r = 1.f / (1.f + expf(-(ir.z + hra.z + hrb.z)));
    float z = 1.f / (1.f + expf(-(iz.z + hza.z + hzb.z)));
    float n = tanhf(in_.z + r * (hna.z + hnb.z));
    o.z = (1.f - z) * n + z * hv.z;
  }
  {
    float r = 1.f / (1.f + expf(-(ir.w + hra.w + hrb.w)));
    float z = 1.f / (1.f + expf(-(iz.w + hza.w + hzb.w)));
    float n = tanhf(in_.w + r * (hna.w + hnb.w));
    o.w = (1.f - z) * n + z * hv.w;
  }
  *(float4*)&h[(size_t)b * HDIM + c] = o;
}

// ---------------------------------------------------------------- attn + gh (merged)
// Blocks [0, nattn): fused one-pass attention on h_t (HBM-bound).
// r7 proven form: k += 8 strided -> the block's 8 waves march lockstep
// through ADJACENT rows = one contiguous moving window per block (r12's
// per-wave chunks fragmented locality, +25us/step -- reverted).
// Blocks [nattn, nattn+384): gh_{t+1} partials = h_t @ W_hh^T (VALU-bound).
#define SMEM_BYTES 37440
__global__ __launch_bounds__(512) void attn_gh_kernel(
    const float* __restrict__ h, const float* __restrict__ enc,
    const float* __restrict__ sem, const float* __restrict__ emb,
    float* __restrict__ x, float* __restrict__ out, int t,
    const float* __restrict__ W_hh, const float* __restrict__ b_hh,
    float* __restrict__ gh, int nattn) {
  __shared__ __align__(16) char smem[SMEM_BYTES];
  const int tid = threadIdx.x;
  if ((int)blockIdx.x < nattn) {
    // ------------- attention branch (8 waves)
    float* hs = reinterpret_cast<float*>(smem);                         // [1024]
    float (*accb)[HDIM] = reinterpret_cast<float (*)[HDIM]>(smem + 4096); // [8][1024]
    float* uls = reinterpret_cast<float*>(smem + 36864);                // [129]
    float* usums = reinterpret_cast<float*>(smem + 37392);              // [8]
    const int b = blockIdx.x;
    const int lane = tid & 63, wv = tid >> 6;

    *(float2*)&hs[tid * 2] = *(const float2*)&h[(size_t)b * HDIM + tid * 2];
    __syncthreads();

    const int l4 = lane * 4;
    float4 hv0 = *(const float4*)&hs[l4];
    float4 hv1 = *(const float4*)&hs[l4 + 256];
    float4 hv2 = *(const float4*)&hs[l4 + 512];
    float4 hv3 = *(const float4*)&hs[l4 + 768];

    float4 acc0 = {0, 0, 0, 0}, acc1 = {0, 0, 0, 0};
    float4 acc2 = {0, 0, 0, 0}, acc3 = {0, 0, 0, 0};
    float usum = 0.f;

    for (int k = wv; k < SEQ + 1; k += 8) {
      const float* kr;
      const float* vr;
      if (k < SEQ) {
        kr = enc + ((size_t)b * SEQ + k) * HDIM;
        vr = sem + ((size_t)b * SEQ + k) * HDIM;
      } else {
        kr = emb + (size_t)VOUT * HDIM;
        vr = emb + (size_t)(VOUT + 1) * HDIM;
      }
      float4 e0 = *(const float4*)(kr + l4);
      float4 e1 = *(const float4*)(kr + l4 + 256);
      float4 e2 = *(const float4*)(kr + l4 + 512);
      float4 e3 = *(const float4*)(kr + l4 + 768);
      float4 v0 = *(const float4*)(vr + l4);
      float4 v1 = *(const float4*)(vr + l4 + 256);
      float4 v2 = *(const float4*)(vr + l4 + 512);
      float4 v3 = *(const float4*)(vr + l4 + 768);

      float p = 0.f;
      p = fmaf(e0.x, hv0.x, p); p = fmaf(e0.y, hv0.y, p);
      p = fmaf(e0.z, hv0.z, p); p = fmaf(e0.w, hv0.w, p);
      p = fmaf(e1.x, hv1.x, p); p = fmaf(e1.y, hv1.y, p);
      p = fmaf(e1.z, hv1.z, p); p = fmaf(e1.w, hv1.w, p);
      p = fmaf(e2.x, hv2.x, p); p = fmaf(e2.y, hv2.y, p);
      p = fmaf(e2.z, hv2.z, p); p = fmaf(e2.w, hv2.w, p);
      p = fmaf(e3.x, hv3.x, p); p = fmaf(e3.y, hv3.y, p);
      p = fmaf(e3.z, hv3.z, p); p = fmaf(e3.w, hv3.w, p);
#pragma unroll
      for (int off = 32; off; off >>= 1) p += __shfl_xor(p, off);

      float u = expf(p * 0.03125f);  // * 1/sqrt(1024)
      usum += u;
      if (lane == 0) uls[k] = u;

      acc0.x = fmaf(u, v0.x, acc0.x); acc0.y = fmaf(u, v0.y, acc0.y);
      acc0.z = fmaf(u, v0.z, acc0.z); acc0.w = fmaf(u, v0.w, acc0.w);
      acc1.x = fmaf(u, v1.x, acc1.x); acc1.y = fmaf(u, v1.y, acc1.y);
      acc1.z = fmaf(u, v1.z, acc1.z); acc1.w = fmaf(u, v1.w, acc1.w);
      acc2.x = fmaf(u, v2.x, acc2.x); acc2.y = fmaf(u, v2.y, acc2.y);
      acc2.z = fmaf(u, v2.z, acc2.z); acc2.w = fmaf(u, v2.w, acc2.w);
      acc3.x = fmaf(u, v3.x, acc3.x); acc3.y = fmaf(u, v3.y, acc3.y);
      acc3.z = fmaf(u, v3.z, acc3.z); acc3.w = fmaf(u, v3.w, acc3.w);
    }

    if (lane == 0) usums[wv] = usum;
    *(float4*)&accb[wv][l4] = acc0;
    *(float4*)&accb[wv][l4 + 256] = acc1;
    *(float4*)&accb[wv][l4 + 512] = acc2;
    *(float4*)&accb[wv][l4 + 768] = acc3;
    __syncthreads();

    float U = 0.f;
#pragma unroll
    for (int w = 0; w < 8; ++w) U += usums[w];
    float rinv = 1.f / U;

#pragma unroll
    for (int dd = 0; dd < 2; ++dd) {
      int d = tid + dd * 512;
      float sum = 0.f;
#pragma unroll
      for (int w = 0; w < 8; ++w) sum += accb[w][d];
      x[(size_t)b * HDIM + d] = sum * rinv + hs[d];
    }

    if (tid < SEQ + 1)
      out[WS_OFF + ((size_t)b * TSTEPS + t) * (SEQ + 1) + tid] = uls[tid] * rinv;
  } else {
    // ------------- gh GEMM branch: BM=128, BN=64, BK=32, K-split 2
    float (*Als)[132] = reinterpret_cast<float (*)[132]>(smem);          // 16896 B
    float (*Bls)[68] = reinterpret_cast<float (*)[68]>(smem + 16896);    // 8704 B
    int gb = blockIdx.x - nattn;
    const int z = gb / 192; gb -= z * 192;
    const int by = gb / 48, bx = gb - by * 48;
    const int m0 = by * 128, n0 = bx * 64;
    const int kbeg = z * 512;
    const int tx = tid & 15, ty = tid >> 4;   // ty 0..31 (A rows), tx 0..15 (B cols)
    const int sr = tid >> 3;                  // 0..63
    const int scol = (tid & 7) << 2;          // 0..28
    const int ca = sr ^ scol;

    const float* a0 = h + (size_t)(m0 + sr) * HDIM + kbeg + scol;
    const float* a1 = h + (size_t)(m0 + sr + 64) * HDIM + kbeg + scol;
    const float* w0 = W_hh + (size_t)(n0 + sr) * HDIM + kbeg + scol;

    float accT[4][4];
#pragma unroll
    for (int i = 0; i < 4; ++i)
#pragma unroll
      for (int j = 0; j < 4; ++j) accT[i][j] = 0.f;

    float4 av0 = *(const float4*)(a0);
    float4 av1 = *(const float4*)(a1);
    float4 wv0 = *(const float4*)(w0);

    for (int k0 = 0; k0 < 512; k0 += 32) {
      __syncthreads();
      Als[scol + 0][ca] = av0.x; Als[scol + 1][ca] = av0.y;
      Als[scol + 2][ca] = av0.z; Als[scol + 3][ca] = av0.w;
      Als[scol + 0][ca + 64] = av1.x; Als[scol + 1][ca + 64] = av1.y;
      Als[scol + 2][ca + 64] = av1.z; Als[scol + 3][ca + 64] = av1.w;
      Bls[scol + 0][ca] = wv0.x; Bls[scol + 1][ca] = wv0.y;
      Bls[scol + 2][ca] = wv0.z; Bls[scol + 3][ca] = wv0.w;
      __syncthreads();

      {
        const int kn = min(k0 + 32, 512 - 32);
        av0 = *(const float4*)(a0 + kn);
        av1 = *(const float4*)(a1 + kn);
        wv0 = *(const float4*)(w0 + kn);
      }

      float ac[4][4];
#pragma unroll
      for (int i = 0; i < 4; ++i)
#pragma unroll
        for (int j = 0; j < 4; ++j) ac[i][j] = 0.f;

#pragma unroll
      for (int kk = 0; kk < 32; ++kk) {
        const int sz = kk & 28;
        float4 a4 = *(const float4*)&Als[kk][(ty * 4) ^ sz];
        float4 b4 = *(const float4*)&Bls[kk][(tx * 4) ^ sz];
        float a_[4] = {a4.x, a4.y, a4.z, a4.w};
        float b_[4] = {b4.x, b4.y, b4.z, b4.w};
#pragma unroll
        for (int i = 0; i < 4; ++i)
#pragma unroll
          for (int j = 0; j < 4; ++j) ac[i][j] = fmaf(a_[i], b_[j], ac[i][j]);
      }
#pragma unroll
      for (int i = 0; i < 4; ++i)
#pragma unroll
        for (int j = 0; j < 4; ++j) accT[i][j] += ac[i][j];
    }

    float* Cz = gh + (size_t)z * (NB * 3 * HDIM);
    float b0 = 0.f, b1 = 0.f, b2 = 0.f, b3 = 0.f;
    if (z == 0) {
      b0 = b_hh[n0 + tx * 4 + 0];
      b1 = b_hh[n0 + tx * 4 + 1];
      b2 = b_hh[n0 + tx * 4 + 2];
      b3 = b_hh[n0 + tx * 4 + 3];
    }
#pragma unroll
    for (int i = 0; i < 4; ++i) {
      int m = m0 + ty * 4 + i;
      float4 o;
      o.x = accT[i][0] + b0;
      o.y = accT[i][1] + b1;
      o.z = accT[i][2] + b2;
      o.w = accT[i][3] + b3;
      *(float4*)&Cz[(size_t)m * (3 * HDIM) + n0 + tx * 4] = o;
    }
  }
}

// ---------------------------------------------------------------- finalize + gate
// Single-plane logits (gemm64 gives 512 blocks unsplit -> no K-split needed).
// Single pass: argmax/lse/entropy, then apply next step's GRU gate -> h_{t+1}.
__global__ __launch_bounds__(256) void finalgate_kernel(
    const float* __restrict__ logits, float* __restrict__ out, int t,
    const float* __restrict__ E2, const float* __restrict__ gh,
    float* __restrict__ h) {
  const int b = blockIdx.x, tid = threadIdx.x;
  const int lane = tid & 63, wv = tid >> 6;
  const float* lrow = logits + (size_t)b * VOUT;
  float m = -3.4e38f; int mi = 0;
  float s = 0.f, ts = 0.f;
#pragma unroll
  for (int it = 0; it < 4; ++it) {
    int j = (tid << 2) + (it << 10);
    float4 v = *(const float4*)&lrow[j];
    float e;
    e = expf(v.x); s += e; ts = fmaf(e, v.x, ts); if (v.x > m) { m = v.x; mi = j; }
    e = expf(v.y); s += e; ts = fmaf(e, v.y, ts); if (v.y > m) { m = v.y; mi = j + 1; }
    e = expf(v.z); s += e; ts = fmaf(e, v.z, ts); if (v.z > m) { m = v.z; mi = j + 2; }
    e = expf(v.w); s += e; ts = fmaf(e, v.w, ts); if (v.w > m) { m = v.w; mi = j + 3; }
  }
#pragma unroll
  for (int off = 32; off; off >>= 1) {
    float om = __shfl_xor(m, off);
    int oi = __shfl_xor(mi, off);
    s += __shfl_xor(s, off);
    ts += __shfl_xor(ts, off);
    if (om > m || (om == m && oi < mi)) { m = om; mi = oi; }
  }
  __shared__ float smx[4], ssm[4], sts[4];
  __shared__ int smi[4];
  __shared__ int mib;
  if (lane == 0) { smx[wv] = m; smi[wv] = mi; ssm[wv] = s; sts[wv] = ts; }
  __syncthreads();
  if (tid == 0) {
#pragma unroll
    for (int w = 1; w < 4; ++w) {
      s += ssm[w]; ts += sts[w];
      if (smx[w] > m || (smx[w] == m && smi[w] < mi)) { m = smx[w]; mi = smi[w]; }
    }
    float lse = logf(s);
    float lp = m - lse;
    float ent = lse - ts / s;
    out[SEQ_OFF + (size_t)b * 33 + t] = (float)mi;
    out[LP_OFF  + (size_t)b * 33 + t] = lp;
    out[ENT_OFF + (size_t)b * 33 + t] = ent;
    mib = mi;
  }
  __syncthreads();

  // ---- gate for next step: h[b] = GRU(E2[mib], gh[b], h[b])
  const int c = tid << 2;
  const float* e = E2 + (size_t)mib * (3 * HDIM) + c;
  const float* g0 = gh + (size_t)b * (3 * HDIM) + c;
  const float* g1 = g0 + (size_t)NB * 3 * HDIM;
  float4 ir = *(const float4*)(e);
  float4 iz = *(const float4*)(e + HDIM);
  float4 in_ = *(const float4*)(e + 2 * HDIM);
  float4 hra = *(const float4*)(g0);
  float4 hza = *(const float4*)(g0 + HDIM);
  float4 hna = *(const float4*)(g0 + 2 * HDIM);
  float4 hrb = *(const float4*)(g1);
  float4 hzb = *(const float4*)(g1 + HDIM);
  float4 hnb = *(const float4*)(g1 + 2 * HDIM);
  float4 hv = *(const float4*)&h[(size_t)b * HDIM + c];
  float4 o;
  {
    float r = 1.f / (1.f + expf(-(ir.x + hra.x + hrb.x)));
    float z = 1.f / (1.f + expf(-(iz.x + hza.x + hzb.x)));
    float n = tanhf(in_.x + r * (hna.x + hnb.x));
    o.x = (1.f - z) * n + z * hv.x;
  }
  {
    float r = 1.f / (1.f + expf(-(ir.y + hra.y + hrb.y)));
    float z = 1.f / (1.f + expf(-(iz.y + hza.y + hzb.y)));
    float n = tanhf(in_.y + r * (hna.y + hnb.y));
    o.y = (1.f - z) * n + z * hv.y;
  }
  {
    float r = 1.f / (1.f + expf(-(ir.z + hra.z + hrb.z)));
    float z = 1.f / (1.f + expf(-(iz.z + hza.z + hzb.z)));
    float n = tanhf(in_.z + r * (hna.z + hnb.z));
    o.z = (1.f - z) * n + z * hv.z;
  }
  {
    float r = 1.f / (1.f + expf(-(ir.w + hra.w + hrb.w)));
    float z = 1.f / (1.f + expf(-(iz.w + hza.w + hzb.w)));
    float n = tanhf(in_.w + r * (hna.w + hnb.w));
    o.w = (1.f - z) * n + z * hv.w;
  }
  *(float4*)&h[(size_t)b * HDIM + c] = o;
}

// ---------------------------------------------------------------- launch
extern "C" void kernel_launch(void* const* d_in, const int* in_sizes, int n_in,
                              void* d_out, int out_size, void* d_ws, size_t ws_size,
                              hipStream_t stream) {
  const float* enc   = (const float*)d_in[0];
  const float* sem   = (const float*)d_in[1];
  const float* emb   = (const float*)d_in[2];
  const float* W_ih  = (const float*)d_in[3];
  const float* W_hh  = (const float*)d_in[4];
  const float* b_ih  = (const float*)d_in[5];
  const float* b_hh  = (const float*)d_in[6];
  const float* W_out = (const float*)d_in[7];
  const float* b_out = (const float*)d_in[8];
  float* out = (float*)d_out;

  float* h      = (float*)d_ws;                        // 512*1024
  float* x      = h + (size_t)NB * HDIM;               // 512*1024
  float* gh     = x + (size_t)NB * HDIM;               // 2 * 512*3072 (K-split)
  float* logits = gh + (size_t)2 * NB * 3 * HDIM;      // 512*4096 (single plane)
  float* E2     = logits + (size_t)NB * VOUT;          // 4160*3072
  int*   tok    = (int*)(E2 + (size_t)EROWS * 3 * HDIM);

  init_kernel<<<2048, 256, 0, stream>>>(h, tok, out);
  // E2 = embedding @ W_ih^T + b_ih  (once per launch; rows clamped at 4099)
  gemm64_kernel<<<dim3(48, 65, 1), 256, 0, stream>>>(emb, W_ih, b_ih, E2,
                                                     3 * HDIM, VOUT + 3, HDIM, 0);
  // gh_0 partials from h=0 (gemm branch only), then gate_0 with SOS tokens
  attn_gh_kernel<<<384, 512, 0, stream>>>(h, enc, sem, emb, x, out, 0,
                                          W_hh, b_hh, gh, 0);
  gate_kernel<<<512, 256, 0, stream>>>(E2, gh, tok, h);

  for (int t = 0; t < TSTEPS; ++t) {
    // attn_t (512 blocks) || gh_{t+1} partials (384 blocks)
    attn_gh_kernel<<<896, 512, 0, stream>>>(h, enc, sem, emb, x, out, t,
                                            W_hh, b_hh, gh, 512);
    // logits: 512 blocks (2/CU exact), no K-split
    gemm64_kernel<<<dim3(64, 8, 1), 256, 0, stream>>>(x, W_out, b_out, logits,
                                                      VOUT, NB, HDIM, 0);
    finalgate_kernel<<<512, 256, 0, stream>>>(logits, out, t, E2, gh, h);
  }
}

// Round 14
// 7093.087 us; speedup vs baseline: 1.1279x; 1.0594x over previous
//
#include <hip/hip_runtime.h>
#include <stdint.h>

// Problem constants
#define HDIM 1024
#define NB   512
#define SEQ  128
#define VOUT 4096
#define TSTEPS 32
#define EROWS 4160   // padded E2 rows (4099 valid, rest garbage-but-deterministic)

// Output layout (float elements, concatenated in reference return order)
#define SEQ_OFF 0
#define LP_OFF  16896   // 512*33
#define ENT_OFF 33792   // 2*512*33
#define WS_OFF  50688   // 3*512*33

// ---------------------------------------------------------------- init
__global__ void init_kernel(float* __restrict__ h, int* __restrict__ tok,
                            float* __restrict__ out) {
  int idx = blockIdx.x * blockDim.x + threadIdx.x;   // 2048*256 = NB*HDIM
  h[idx] = 0.f;
  if (idx < NB) {
    tok[idx] = VOUT + 2;                             // SOS token
    out[SEQ_OFF + idx * 33 + 32] = 0.f;              // zero tail column
    out[LP_OFF  + idx * 33 + 32] = 0.f;
    out[ENT_OFF + idx * 33 + 32] = 0.f;
  }
}

// ---------------------------------------------------------------- GEMM64
// r5 proven version — best for E2 (368us, VGPR 36, 0 conflicts, VALUBusy 67%).
__global__ __launch_bounds__(256) void gemm64_kernel(
    const float* __restrict__ A, const float* __restrict__ W,
    const float* __restrict__ bias, float* __restrict__ C,
    int N, int Mlim, int KLEN, int zstride) {
  __shared__ __align__(16) float Als[32][68];
  __shared__ __align__(16) float Bls[32][68];
  const int tid = threadIdx.x;
  const int tx = tid & 15, ty = tid >> 4;
  const int m0 = blockIdx.y * 64, n0 = blockIdx.x * 64;
  const int z = blockIdx.z;
  const int kbeg = z * KLEN;
  const int sr = tid >> 3;          // 0..31
  const int scol = (tid & 7) << 2;  // 0..28

  const int ca0 = sr ^ scol;
  const int ca1 = (sr + 32) ^ scol;

  const int ra = min(m0 + sr, Mlim - 1);
  const int rb = min(m0 + sr + 32, Mlim - 1);
  const float* a0 = A + (size_t)ra * HDIM + kbeg + scol;
  const float* a1 = A + (size_t)rb * HDIM + kbeg + scol;
  const float* w0 = W + (size_t)(n0 + sr) * HDIM + kbeg + scol;
  const float* w1 = W + (size_t)(n0 + sr + 32) * HDIM + kbeg + scol;

  float accT[4][4];
#pragma unroll
  for (int i = 0; i < 4; ++i)
#pragma unroll
    for (int j = 0; j < 4; ++j) accT[i][j] = 0.f;

  float4 av0 = *(const float4*)(a0);
  float4 av1 = *(const float4*)(a1);
  float4 wv0 = *(const float4*)(w0);
  float4 wv1 = *(const float4*)(w1);

  for (int k0 = 0; k0 < KLEN; k0 += 32) {
    __syncthreads();
    Als[scol + 0][ca0] = av0.x; Als[scol + 1][ca0] = av0.y;
    Als[scol + 2][ca0] = av0.z; Als[scol + 3][ca0] = av0.w;
    Als[scol + 0][ca1] = av1.x; Als[scol + 1][ca1] = av1.y;
    Als[scol + 2][ca1] = av1.z; Als[scol + 3][ca1] = av1.w;
    Bls[scol + 0][ca0] = wv0.x; Bls[scol + 1][ca0] = wv0.y;
    Bls[scol + 2][ca0] = wv0.z; Bls[scol + 3][ca0] = wv0.w;
    Bls[scol + 0][ca1] = wv1.x; Bls[scol + 1][ca1] = wv1.y;
    Bls[scol + 2][ca1] = wv1.z; Bls[scol + 3][ca1] = wv1.w;
    __syncthreads();

    {
      const int kn = min(k0 + 32, KLEN - 32);
      av0 = *(const float4*)(a0 + kn);
      av1 = *(const float4*)(a1 + kn);
      wv0 = *(const float4*)(w0 + kn);
      wv1 = *(const float4*)(w1 + kn);
    }

    // chunk accumulator (flushed per BK) keeps error ~5 eps
    float ac[4][4];
#pragma unroll
    for (int i = 0; i < 4; ++i)
#pragma unroll
      for (int j = 0; j < 4; ++j) ac[i][j] = 0.f;

#pragma unroll
    for (int kk = 0; kk < 32; ++kk) {
      const int sz = kk & 28;  // read swizzle (wave-uniform, bits 2-4)
      float4 a4 = *(const float4*)&Als[kk][(ty * 4) ^ sz];
      float4 b4 = *(const float4*)&Bls[kk][(tx * 4) ^ sz];
      float a_[4] = {a4.x, a4.y, a4.z, a4.w};
      float b_[4] = {b4.x, b4.y, b4.z, b4.w};
#pragma unroll
      for (int i = 0; i < 4; ++i)
#pragma unroll
        for (int j = 0; j < 4; ++j) ac[i][j] = fmaf(a_[i], b_[j], ac[i][j]);
    }
#pragma unroll
    for (int i = 0; i < 4; ++i)
#pragma unroll
      for (int j = 0; j < 4; ++j) accT[i][j] += ac[i][j];
  }

  float* Cz = C + (size_t)z * zstride;
  float b0 = 0.f, b1 = 0.f, b2 = 0.f, b3 = 0.f;
  if (z == 0) {
    b0 = bias[n0 + tx * 4 + 0];
    b1 = bias[n0 + tx * 4 + 1];
    b2 = bias[n0 + tx * 4 + 2];
    b3 = bias[n0 + tx * 4 + 3];
  }
#pragma unroll
  for (int i = 0; i < 4; ++i) {
    int m = m0 + ty * 4 + i;
    float4 o;
    o.x = accT[i][0] + b0;
    o.y = accT[i][1] + b1;
    o.z = accT[i][2] + b2;
    o.w = accT[i][3] + b3;
    *(float4*)&Cz[(size_t)m * N + n0 + tx * 4] = o;
  }
}

// ---------------------------------------------------------------- GEMM128x64
// r7 version — best for in-loop logits (K-split=2, 512 blocks; r7 in-loop
// beat gemm64-Ksplit by 2.6us/step and gemm64-unsplit by 13us/step).
__global__ __launch_bounds__(256) void gemm128_kernel(
    const float* __restrict__ A, const float* __restrict__ W,
    const float* __restrict__ bias, float* __restrict__ C,
    int N, int Mlim, int KLEN, int zstride) {
  __shared__ __align__(16) float Als[32][132];
  __shared__ __align__(16) float Bls[32][68];
  const int tid = threadIdx.x;
  const int tx = tid & 15, ty = tid >> 4;
  const int m0 = blockIdx.y * 128, n0 = blockIdx.x * 64;
  const int z = blockIdx.z;
  const int kbeg = z * KLEN;
  const int sr = tid >> 3;          // 0..31
  const int scol = (tid & 7) << 2;  // 0..28

  const int ca = sr ^ scol;         // phys col for row sr; +32i for rows sr+32i

  const float* a0 = A + (size_t)min(m0 + sr,      Mlim - 1) * HDIM + kbeg + scol;
  const float* a1 = A + (size_t)min(m0 + sr + 32, Mlim - 1) * HDIM + kbeg + scol;
  const float* a2 = A + (size_t)min(m0 + sr + 64, Mlim - 1) * HDIM + kbeg + scol;
  const float* a3 = A + (size_t)min(m0 + sr + 96, Mlim - 1) * HDIM + kbeg + scol;
  const float* w0 = W + (size_t)(n0 + sr) * HDIM + kbeg + scol;
  const float* w1 = W + (size_t)(n0 + sr + 32) * HDIM + kbeg + scol;

  float accT[8][4];
#pragma unroll
  for (int i = 0; i < 8; ++i)
#pragma unroll
    for (int j = 0; j < 4; ++j) accT[i][j] = 0.f;

  float4 av0 = *(const float4*)(a0);
  float4 av1 = *(const float4*)(a1);
  float4 av2 = *(const float4*)(a2);
  float4 av3 = *(const float4*)(a3);
  float4 wv0 = *(const float4*)(w0);
  float4 wv1 = *(const float4*)(w1);

  for (int k0 = 0; k0 < KLEN; k0 += 32) {
    __syncthreads();
    Als[scol + 0][ca] = av0.x; Als[scol + 1][ca] = av0.y;
    Als[scol + 2][ca] = av0.z; Als[scol + 3][ca] = av0.w;
    Als[scol + 0][ca + 32] = av1.x; Als[scol + 1][ca + 32] = av1.y;
    Als[scol + 2][ca + 32] = av1.z; Als[scol + 3][ca + 32] = av1.w;
    Als[scol + 0][ca + 64] = av2.x; Als[scol + 1][ca + 64] = av2.y;
    Als[scol + 2][ca + 64] = av2.z; Als[scol + 3][ca + 64] = av2.w;
    Als[scol + 0][ca + 96] = av3.x; Als[scol + 1][ca + 96] = av3.y;
    Als[scol + 2][ca + 96] = av3.z; Als[scol + 3][ca + 96] = av3.w;
    Bls[scol + 0][ca] = wv0.x; Bls[scol + 1][ca] = wv0.y;
    Bls[scol + 2][ca] = wv0.z; Bls[scol + 3][ca] = wv0.w;
    Bls[scol + 0][ca + 32] = wv1.x; Bls[scol + 1][ca + 32] = wv1.y;
    Bls[scol + 2][ca + 32] = wv1.z; Bls[scol + 3][ca + 32] = wv1.w;
    __syncthreads();

    {
      const int kn = min(k0 + 32, KLEN - 32);
      av0 = *(const float4*)(a0 + kn);
      av1 = *(const float4*)(a1 + kn);
      av2 = *(const float4*)(a2 + kn);
      av3 = *(const float4*)(a3 + kn);
      wv0 = *(const float4*)(w0 + kn);
      wv1 = *(const float4*)(w1 + kn);
    }

    float ac[8][4];
#pragma unroll
    for (int i = 0; i < 8; ++i)
#pragma unroll
      for (int j = 0; j < 4; ++j) ac[i][j] = 0.f;

#pragma unroll
    for (int kk = 0; kk < 32; ++kk) {
      const int sz = kk & 28;
      float4 aLo = *(const float4*)&Als[kk][(ty * 4) ^ sz];
      float4 aHi = *(const float4*)&Als[kk][64 + ((ty * 4) ^ sz)];
      float4 b4  = *(const float4*)&Bls[kk][(tx * 4) ^ sz];
      float a_[8] = {aLo.x, aLo.y, aLo.z, aLo.w, aHi.x, aHi.y, aHi.z, aHi.w};
      float b_[4] = {b4.x, b4.y, b4.z, b4.w};
#pragma unroll
      for (int i = 0; i < 8; ++i)
#pragma unroll
        for (int j = 0; j < 4; ++j) ac[i][j] = fmaf(a_[i], b_[j], ac[i][j]);
    }
#pragma unroll
    for (int i = 0; i < 8; ++i)
#pragma unroll
      for (int j = 0; j < 4; ++j) accT[i][j] += ac[i][j];
  }

  float* Cz = C + (size_t)z * zstride;
  float b0 = 0.f, b1 = 0.f, b2 = 0.f, b3 = 0.f;
  if (z == 0) {
    b0 = bias[n0 + tx * 4 + 0];
    b1 = bias[n0 + tx * 4 + 1];
    b2 = bias[n0 + tx * 4 + 2];
    b3 = bias[n0 + tx * 4 + 3];
  }
#pragma unroll
  for (int q = 0; q < 2; ++q) {
#pragma unroll
    for (int i = 0; i < 4; ++i) {
      int m = m0 + q * 64 + ty * 4 + i;
      if (m >= Mlim) continue;
      float4 o;
      o.x = accT[q * 4 + i][0] + b0;
      o.y = accT[q * 4 + i][1] + b1;
      o.z = accT[q * 4 + i][2] + b2;
      o.w = accT[q * 4 + i][3] + b3;
      *(float4*)&Cz[(size_t)m * N + n0 + tx * 4] = o;
    }
  }
}

// ---------------------------------------------------------------- gate (pre-loop only)
__global__ __launch_bounds__(256) void gate_kernel(
    const float* __restrict__ E2, const float* __restrict__ gh,
    const int* __restrict__ tok, float* __restrict__ h) {
  int idx = blockIdx.x * blockDim.x + threadIdx.x;
  int b = idx >> 8;
  int c = (idx & 255) << 2;
  const float* e = E2 + (size_t)tok[b] * (3 * HDIM) + c;
  const float* g0 = gh + (size_t)b * (3 * HDIM) + c;
  const float* g1 = g0 + (size_t)NB * 3 * HDIM;
  float4 ir = *(const float4*)(e);
  float4 iz = *(const float4*)(e + HDIM);
  float4 in_ = *(const float4*)(e + 2 * HDIM);
  float4 hra = *(const float4*)(g0);
  float4 hza = *(const float4*)(g0 + HDIM);
  float4 hna = *(const float4*)(g0 + 2 * HDIM);
  float4 hrb = *(const float4*)(g1);
  float4 hzb = *(const float4*)(g1 + HDIM);
  float4 hnb = *(const float4*)(g1 + 2 * HDIM);
  float4 hv = *(const float4*)&h[(size_t)b * HDIM + c];
  float4 o;
  {
    float r = 1.f / (1.f + expf(-(ir.x + hra.x + hrb.x)));
    float z = 1.f / (1.f + expf(-(iz.x + hza.x + hzb.x)));
    float n = tanhf(in_.x + r * (hna.x + hnb.x));
    o.x = (1.f - z) * n + z * hv.x;
  }
  {
    float r = 1.f / (1.f + expf(-(ir.y + hra.y + hrb.y)));
    float z = 1.f / (1.f + expf(-(iz.y + hza.y + hzb.y)));
    float n = tanhf(in_.y + r * (hna.y + hnb.y));
    o.y = (1.f - z) * n + z * hv.y;
  }
  {
    float r = 1.f / (1.f + expf(-(ir.z + hra.z + hrb.z)));
    float z = 1.f / (1.f + expf(-(iz.z + hza.z + hzb.z)));
    float n = tanhf(in_.z + r * (hna.z + hnb.z));
    o.z = (1.f - z) * n + z * hv.z;
  }
  {
    float r = 1.f / (1.f + expf(-(ir.w + hra.w + hrb.w)));
    float z = 1.f / (1.f + expf(-(iz.w + hza.w + hzb.w)));
    float n = tanhf(in_.w + r * (hna.w + hnb.w));
    o.w = (1.f - z) * n + z * hv.w;
  }
  *(float4*)&h[(size_t)b * HDIM + c] = o;
}

// ---------------------------------------------------------------- attn + gh (merged)
// r7 proven form (k += 8 lockstep window; r12 chunk/prefetch variants falsified).
#define SMEM_BYTES 37440
__global__ __launch_bounds__(512) void attn_gh_kernel(
    const float* __restrict__ h, const float* __restrict__ enc,
    const float* __restrict__ sem, const float* __restrict__ emb,
    float* __restrict__ x, float* __restrict__ out, int t,
    const float* __restrict__ W_hh, const float* __restrict__ b_hh,
    float* __restrict__ gh, int nattn) {
  __shared__ __align__(16) char smem[SMEM_BYTES];
  const int tid = threadIdx.x;
  if ((int)blockIdx.x < nattn) {
    float* hs = reinterpret_cast<float*>(smem);                         // [1024]
    float (*accb)[HDIM] = reinterpret_cast<float (*)[HDIM]>(smem + 4096); // [8][1024]
    float* uls = reinterpret_cast<float*>(smem + 36864);                // [129]
    float* usums = reinterpret_cast<float*>(smem + 37392);              // [8]
    const int b = blockIdx.x;
    const int lane = tid & 63, wv = tid >> 6;

    *(float2*)&hs[tid * 2] = *(const float2*)&h[(size_t)b * HDIM + tid * 2];
    __syncthreads();

    const int l4 = lane * 4;
    float4 hv0 = *(const float4*)&hs[l4];
    float4 hv1 = *(const float4*)&hs[l4 + 256];
    float4 hv2 = *(const float4*)&hs[l4 + 512];
    float4 hv3 = *(const float4*)&hs[l4 + 768];

    float4 acc0 = {0, 0, 0, 0}, acc1 = {0, 0, 0, 0};
    float4 acc2 = {0, 0, 0, 0}, acc3 = {0, 0, 0, 0};
    float usum = 0.f;

    for (int k = wv; k < SEQ + 1; k += 8) {
      const float* kr;
      const float* vr;
      if (k < SEQ) {
        kr = enc + ((size_t)b * SEQ + k) * HDIM;
        vr = sem + ((size_t)b * SEQ + k) * HDIM;
      } else {
        kr = emb + (size_t)VOUT * HDIM;
        vr = emb + (size_t)(VOUT + 1) * HDIM;
      }
      float4 e0 = *(const float4*)(kr + l4);
      float4 e1 = *(const float4*)(kr + l4 + 256);
      float4 e2 = *(const float4*)(kr + l4 + 512);
      float4 e3 = *(const float4*)(kr + l4 + 768);
      float4 v0 = *(const float4*)(vr + l4);
      float4 v1 = *(const float4*)(vr + l4 + 256);
      float4 v2 = *(const float4*)(vr + l4 + 512);
      float4 v3 = *(const float4*)(vr + l4 + 768);

      float p = 0.f;
      p = fmaf(e0.x, hv0.x, p); p = fmaf(e0.y, hv0.y, p);
      p = fmaf(e0.z, hv0.z, p); p = fmaf(e0.w, hv0.w, p);
      p = fmaf(e1.x, hv1.x, p); p = fmaf(e1.y, hv1.y, p);
      p = fmaf(e1.z, hv1.z, p); p = fmaf(e1.w, hv1.w, p);
      p = fmaf(e2.x, hv2.x, p); p = fmaf(e2.y, hv2.y, p);
      p = fmaf(e2.z, hv2.z, p); p = fmaf(e2.w, hv2.w, p);
      p = fmaf(e3.x, hv3.x, p); p = fmaf(e3.y, hv3.y, p);
      p = fmaf(e3.z, hv3.z, p); p = fmaf(e3.w, hv3.w, p);
#pragma unroll
      for (int off = 32; off; off >>= 1) p += __shfl_xor(p, off);

      float u = expf(p * 0.03125f);  // * 1/sqrt(1024)
      usum += u;
      if (lane == 0) uls[k] = u;

      acc0.x = fmaf(u, v0.x, acc0.x); acc0.y = fmaf(u, v0.y, acc0.y);
      acc0.z = fmaf(u, v0.z, acc0.z); acc0.w = fmaf(u, v0.w, acc0.w);
      acc1.x = fmaf(u, v1.x, acc1.x); acc1.y = fmaf(u, v1.y, acc1.y);
      acc1.z = fmaf(u, v1.z, acc1.z); acc1.w = fmaf(u, v1.w, acc1.w);
      acc2.x = fmaf(u, v2.x, acc2.x); acc2.y = fmaf(u, v2.y, acc2.y);
      acc2.z = fmaf(u, v2.z, acc2.z); acc2.w = fmaf(u, v2.w, acc2.w);
      acc3.x = fmaf(u, v3.x, acc3.x); acc3.y = fmaf(u, v3.y, acc3.y);
      acc3.z = fmaf(u, v3.z, acc3.z); acc3.w = fmaf(u, v3.w, acc3.w);
    }

    if (lane == 0) usums[wv] = usum;
    *(float4*)&accb[wv][l4] = acc0;
    *(float4*)&accb[wv][l4 + 256] = acc1;
    *(float4*)&accb[wv][l4 + 512] = acc2;
    *(float4*)&accb[wv][l4 + 768] = acc3;
    __syncthreads();

    float U = 0.f;
#pragma unroll
    for (int w = 0; w < 8; ++w) U += usums[w];
    float rinv = 1.f / U;

#pragma unroll
    for (int dd = 0; dd < 2; ++dd) {
      int d = tid + dd * 512;
      float sum = 0.f;
#pragma unroll
      for (int w = 0; w < 8; ++w) sum += accb[w][d];
      x[(size_t)b * HDIM + d] = sum * rinv + hs[d];
    }

    if (tid < SEQ + 1)
      out[WS_OFF + ((size_t)b * TSTEPS + t) * (SEQ + 1) + tid] = uls[tid] * rinv;
  } else {
    // ------------- gh GEMM branch: BM=128, BN=64, BK=32, K-split 2
    float (*Als)[132] = reinterpret_cast<float (*)[132]>(smem);          // 16896 B
    float (*Bls)[68] = reinterpret_cast<float (*)[68]>(smem + 16896);    // 8704 B
    int gb = blockIdx.x - nattn;
    const int z = gb / 192; gb -= z * 192;
    const int by = gb / 48, bx = gb - by * 48;
    const int m0 = by * 128, n0 = bx * 64;
    const int kbeg = z * 512;
    const int tx = tid & 15, ty = tid >> 4;   // ty 0..31 (A rows), tx 0..15 (B cols)
    const int sr = tid >> 3;                  // 0..63
    const int scol = (tid & 7) << 2;          // 0..28
    const int ca = sr ^ scol;

    const float* a0 = h + (size_t)(m0 + sr) * HDIM + kbeg + scol;
    const float* a1 = h + (size_t)(m0 + sr + 64) * HDIM + kbeg + scol;
    const float* w0 = W_hh + (size_t)(n0 + sr) * HDIM + kbeg + scol;

    float accT[4][4];
#pragma unroll
    for (int i = 0; i < 4; ++i)
#pragma unroll
      for (int j = 0; j < 4; ++j) accT[i][j] = 0.f;

    float4 av0 = *(const float4*)(a0);
    float4 av1 = *(const float4*)(a1);
    float4 wv0 = *(const float4*)(w0);

    for (int k0 = 0; k0 < 512; k0 += 32) {
      __syncthreads();
      Als[scol + 0][ca] = av0.x; Als[scol + 1][ca] = av0.y;
      Als[scol + 2][ca] = av0.z; Als[scol + 3][ca] = av0.w;
      Als[scol + 0][ca + 64] = av1.x; Als[scol + 1][ca + 64] = av1.y;
      Als[scol + 2][ca + 64] = av1.z; Als[scol + 3][ca + 64] = av1.w;
      Bls[scol + 0][ca] = wv0.x; Bls[scol + 1][ca] = wv0.y;
      Bls[scol + 2][ca] = wv0.z; Bls[scol + 3][ca] = wv0.w;
      __syncthreads();

      {
        const int kn = min(k0 + 32, 512 - 32);
        av0 = *(const float4*)(a0 + kn);
        av1 = *(const float4*)(a1 + kn);
        wv0 = *(const float4*)(w0 + kn);
      }

      float ac[4][4];
#pragma unroll
      for (int i = 0; i < 4; ++i)
#pragma unroll
        for (int j = 0; j < 4; ++j) ac[i][j] = 0.f;

#pragma unroll
      for (int kk = 0; kk < 32; ++kk) {
        const int sz = kk & 28;
        float4 a4 = *(const float4*)&Als[kk][(ty * 4) ^ sz];
        float4 b4 = *(const float4*)&Bls[kk][(tx * 4) ^ sz];
        float a_[4] = {a4.x, a4.y, a4.z, a4.w};
        float b_[4] = {b4.x, b4.y, b4.z, b4.w};
#pragma unroll
        for (int i = 0; i < 4; ++i)
#pragma unroll
          for (int j = 0; j < 4; ++j) ac[i][j] = fmaf(a_[i], b_[j], ac[i][j]);
      }
#pragma unroll
      for (int i = 0; i < 4; ++i)
#pragma unroll
        for (int j = 0; j < 4; ++j) accT[i][j] += ac[i][j];
    }

    float* Cz = gh + (size_t)z * (NB * 3 * HDIM);
    float b0 = 0.f, b1 = 0.f, b2 = 0.f, b3 = 0.f;
    if (z == 0) {
      b0 = b_hh[n0 + tx * 4 + 0];
      b1 = b_hh[n0 + tx * 4 + 1];
      b2 = b_hh[n0 + tx * 4 + 2];
      b3 = b_hh[n0 + tx * 4 + 3];
    }
#pragma unroll
    for (int i = 0; i < 4; ++i) {
      int m = m0 + ty * 4 + i;
      float4 o;
      o.x = accT[i][0] + b0;
      o.y = accT[i][1] + b1;
      o.z = accT[i][2] + b2;
      o.w = accT[i][3] + b3;
      *(float4*)&Cz[(size_t)m * (3 * HDIM) + n0 + tx * 4] = o;
    }
  }
}

// ---------------------------------------------------------------- finalize + gate
// logits = z0 + z1 (K-split planes). Single pass: argmax/lse/entropy, then
// apply next step's GRU gate for row b -> h_{t+1}.
__global__ __launch_bounds__(256) void finalgate_kernel(
    const float* __restrict__ logits, float* __restrict__ out, int t,
    const float* __restrict__ E2, const float* __restrict__ gh,
    float* __restrict__ h) {
  const int b = blockIdx.x, tid = threadIdx.x;
  const int lane = tid & 63, wv = tid >> 6;
  const float* lrow0 = logits + (size_t)b * VOUT;
  const float* lrow1 = lrow0 + (size_t)NB * VOUT;
  float m = -3.4e38f; int mi = 0;
  float s = 0.f, ts = 0.f;
#pragma unroll
  for (int it = 0; it < 4; ++it) {
    int j = (tid << 2) + (it << 10);
    float4 va = *(const float4*)&lrow0[j];
    float4 vb = *(const float4*)&lrow1[j];
    float4 v;
    v.x = va.x + vb.x; v.y = va.y + vb.y; v.z = va.z + vb.z; v.w = va.w + vb.w;
    float e;
    e = expf(v.x); s += e; ts = fmaf(e, v.x, ts); if (v.x > m) { m = v.x; mi = j; }
    e = expf(v.y); s += e; ts = fmaf(e, v.y, ts); if (v.y > m) { m = v.y; mi = j + 1; }
    e = expf(v.z); s += e; ts = fmaf(e, v.z, ts); if (v.z > m) { m = v.z; mi = j + 2; }
    e = expf(v.w); s += e; ts = fmaf(e, v.w, ts); if (v.w > m) { m = v.w; mi = j + 3; }
  }
#pragma unroll
  for (int off = 32; off; off >>= 1) {
    float om = __shfl_xor(m, off);
    int oi = __shfl_xor(mi, off);
    s += __shfl_xor(s, off);
    ts += __shfl_xor(ts, off);
    if (om > m || (om == m && oi < mi)) { m = om; mi = oi; }
  }
  __shared__ float smx[4], ssm[4], sts[4];
  __shared__ int smi[4];
  __shared__ int mib;
  if (lane == 0) { smx[wv] = m; smi[wv] = mi; ssm[wv] = s; sts[wv] = ts; }
  __syncthreads();
  if (tid == 0) {
#pragma unroll
    for (int w = 1; w < 4; ++w) {
      s += ssm[w]; ts += sts[w];
      if (smx[w] > m || (smx[w] == m && smi[w] < mi)) { m = smx[w]; mi = smi[w]; }
    }
    float lse = logf(s);
    float lp = m - lse;
    float ent = lse - ts / s;
    out[SEQ_OFF + (size_t)b * 33 + t] = (float)mi;
    out[LP_OFF  + (size_t)b * 33 + t] = lp;
    out[ENT_OFF + (size_t)b * 33 + t] = ent;
    mib = mi;
  }
  __syncthreads();

  // ---- gate for next step: h[b] = GRU(E2[mib], gh[b], h[b])
  const int c = tid << 2;
  const float* e = E2 + (size_t)mib * (3 * HDIM) + c;
  const float* g0 = gh + (size_t)b * (3 * HDIM) + c;
  const float* g1 = g0 + (size_t)NB * 3 * HDIM;
  float4 ir = *(const float4*)(e);
  float4 iz = *(const float4*)(e + HDIM);
  float4 in_ = *(const float4*)(e + 2 * HDIM);
  float4 hra = *(const float4*)(g0);
  float4 hza = *(const float4*)(g0 + HDIM);
  float4 hna = *(const float4*)(g0 + 2 * HDIM);
  float4 hrb = *(const float4*)(g1);
  float4 hzb = *(const float4*)(g1 + HDIM);
  float4 hnb = *(const float4*)(g1 + 2 * HDIM);
  float4 hv = *(const float4*)&h[(size_t)b * HDIM + c];
  float4 o;
  {
    float r = 1.f / (1.f + expf(-(ir.x + hra.x + hrb.x)));
    float z = 1.f / (1.f + expf(-(iz.x + hza.x + hzb.x)));
    float n = tanhf(in_.x + r * (hna.x + hnb.x));
    o.x = (1.f - z) * n + z * hv.x;
  }
  {
    float r = 1.f / (1.f + expf(-(ir.y + hra.y + hrb.y)));
    float z = 1.f / (1.f + expf(-(iz.y + hza.y + hzb.y)));
    float n = tanhf(in_.y + r * (hna.y + hnb.y));
    o.y = (1.f - z) * n + z * hv.y;
  }
  {
    float r = 1.f / (1.f + expf(-(ir.z + hra.z + hrb.z)));
    float z = 1.f / (1.f + expf(-(iz.z + hza.z + hzb.z)));
    float n = tanhf(in_.z + r * (hna.z + hnb.z));
    o.z = (1.f - z) * n + z * hv.z;
  }
  {
    float r = 1.f / (1.f + expf(-(ir.w + hra.w + hrb.w)));
    float z = 1.f / (1.f + expf(-(iz.w + hza.w + hzb.w)));
    float n = tanhf(in_.w + r * (hna.w + hnb.w));
    o.w = (1.f - z) * n + z * hv.w;
  }
  *(float4*)&h[(size_t)b * HDIM + c] = o;
}

// ---------------------------------------------------------------- launch
extern "C" void kernel_launch(void* const* d_in, const int* in_sizes, int n_in,
                              void* d_out, int out_size, void* d_ws, size_t ws_size,
                              hipStream_t stream) {
  const float* enc   = (const float*)d_in[0];
  const float* sem   = (const float*)d_in[1];
  const float* emb   = (const float*)d_in[2];
  const float* W_ih  = (const float*)d_in[3];
  const float* W_hh  = (const float*)d_in[4];
  const float* b_ih  = (const float*)d_in[5];
  const float* b_hh  = (const float*)d_in[6];
  const float* W_out = (const float*)d_in[7];
  const float* b_out = (const float*)d_in[8];
  float* out = (float*)d_out;

  float* h      = (float*)d_ws;                        // 512*1024
  float* x      = h + (size_t)NB * HDIM;               // 512*1024
  float* gh     = x + (size_t)NB * HDIM;               // 2 * 512*3072 (K-split)
  float* logits = gh + (size_t)2 * NB * 3 * HDIM;      // 2 * 512*4096 (K-split)
  float* E2     = logits + (size_t)2 * NB * VOUT;      // 4160*3072
  int*   tok    = (int*)(E2 + (size_t)EROWS * 3 * HDIM);

  init_kernel<<<2048, 256, 0, stream>>>(h, tok, out);
  // E2 = embedding @ W_ih^T + b_ih  (once; gemm64 = best E2: 368us)
  gemm64_kernel<<<dim3(48, 65, 1), 256, 0, stream>>>(emb, W_ih, b_ih, E2,
                                                     3 * HDIM, VOUT + 3, HDIM, 0);
  // gh_0 partials from h=0 (gemm branch only), then gate_0 with SOS tokens
  attn_gh_kernel<<<384, 512, 0, stream>>>(h, enc, sem, emb, x, out, 0,
                                          W_hh, b_hh, gh, 0);
  gate_kernel<<<512, 256, 0, stream>>>(E2, gh, tok, h);

  for (int t = 0; t < TSTEPS; ++t) {
    // attn_t (512 blocks) || gh_{t+1} partials (384 blocks)
    attn_gh_kernel<<<896, 512, 0, stream>>>(h, enc, sem, emb, x, out, t,
                                            W_hh, b_hh, gh, 512);
    // logits partials: gemm128 K-split=2 -> 512 blocks (r7's in-loop winner)
    gemm128_kernel<<<dim3(64, 4, 2), 256, 0, stream>>>(x, W_out, b_out, logits,
                                                       VOUT, NB, HDIM / 2,
                                                       NB * VOUT);
    finalgate_kernel<<<512, 256, 0, stream>>>(logits, out, t, E2, gh, h);
  }
}